// Round 14
// baseline (175.902 us; speedup 1.0000x reference)
//
#include <hip/hip_runtime.h>

// r30 = r29 resubmitted with two DEFENSIVE changes (r29 died "container
// failed twice" — r22 precedent says infra-flake, but a broken 2-blocks/CU
// co-residency in mega_gcn would ALSO present as a timeout via 2^22-spin
// barriers x many reps; these changes make that mode fail fast+visibly):
//   1. spin cap 2^22 -> 2^18 (~13ms/barrier worst case; unreached when
//      barriers work, so perf measurement is unconfounded)
//   2. __launch_bounds__(256,2) on mega_gcn (pins VGPR<=256; r28 measured
//      144, so no pressure — just makes 2-blocks/CU capacity explicit)
// Thesis unchanged: mega_gcn (measured 56.5us, the dominant half) gets 2x
// TLP via 512 blocks x 256 thr (2 blocks/CU, no LDS) + TPP=8 SPLIT gather
// (lane l loads neighbors k%8==l — rows loaded once, unlike r21's
// confounded duplicate-load test) + __shfl_xor butterfly combine.
// Reassociated 9-way sum -> absmax drift ~1e-6 vs 9.9e-2 threshold.
// Decision rules: gcn>=50us or total>=163 -> revert r27; absmax fail ->
// revert r27; third container failure -> revert r27.

// Problem constants (fixed by setup_inputs)
constexpr int NPTS = 16384;
constexpr int KNB  = 9;
constexpr int CDIM = 16;
constexpr int HDIM = 32;

// Spatial grid: FIXED bounds (data ~ N(0,1)).
constexpr int   G    = 128;
constexpr int   GC   = G * G;
constexpr float GMIN = -3.3f;
constexpr float GMAX =  3.3f;
constexpr float CW   = (GMAX - GMIN) / G;
constexpr float INVW = G / (GMAX - GMIN);
constexpr float FBIG = 3.0e38f;

// Ring cap (r12/r13 measured absmax 0.0078 vs threshold 9.9e-2).
constexpr int RCAP = 5;

// FRONT geometry: 4 lanes per point, 256 blocks x 256 threads, 1 block/CU.
constexpr int LPP     = 4;
constexpr int KTHR    = 256;
constexpr int PPB     = KTHR / LPP;      // 64 points per block
constexpr int NBLK    = NPTS / PPB;      // 256 blocks
constexpr int CAPN    = 5120;            // max staged candidates (40 KB)
constexpr int ROWSCAP = 40;              // max staged cell rows (~10 KB)

// GCN geometry: 8 lanes per point (split gather), 512 blocks x 256 threads,
// 2 blocks/CU (no LDS, VGPR pinned <=256 by launch_bounds).
constexpr int TPP2    = 8;
constexpr int PPB2    = KTHR / TPP2;     // 32 points per block
constexpr int NBLK2   = NPTS / PPB2;     // 512 blocks

// Tree-barrier geometry (r23-proven): 16 groups, padded 128B lines.
constexpr int NGRP    = 16;
constexpr int CSTRIDE = 32;              // ints per counter line (128 B)
constexpr int CPB     = NGRP + 1;        // group counters + root
constexpr int NBARS   = 4;               // front barriers (0-3)
constexpr int NBARS2  = 7;               // gcn inter-layer barriers (0-6)
constexpr int BARINTS  = NBARS  * CPB * CSTRIDE;
constexpr int BARINTS2 = NBARS2 * CPB * CSTRIDE;
constexpr int SPINCAP  = 1 << 18;        // ~13ms worst case — fail fast

// Bijective XCD swizzles (r27-proven: FETCH 20.2->9.6MB).
__device__ __forceinline__ int swz_bid (int b) { return (b & 7) * (NBLK  / 8) + (b >> 3); }
__device__ __forceinline__ int swz_bid2(int b) { return (b & 7) * (NBLK2 / 8) + (b >> 3); }

// ---------------------------------------------------------------------------
// WT stores (sc0 sc1) + coherent loads for intra-launch-written lines.
// ---------------------------------------------------------------------------
typedef float f32x4_t __attribute__((ext_vector_type(4)));
typedef float f32x2_t __attribute__((ext_vector_type(2)));

__device__ __forceinline__ void stq_wt(float* p, float4 v) {
    f32x4_t w; w.x = v.x; w.y = v.y; w.z = v.z; w.w = v.w;
    asm volatile("global_store_dwordx4 %0, %1, off sc0 sc1"
                 :: "v"(p), "v"(w) : "memory");
}
__device__ __forceinline__ void st2_wt(float* p, float2 v) {
    f32x2_t w; w.x = v.x; w.y = v.y;
    asm volatile("global_store_dwordx2 %0, %1, off sc0 sc1"
                 :: "v"(p), "v"(w) : "memory");
}
__device__ __forceinline__ void st1_wt(int* p, int v) {
    asm volatile("global_store_dword %0, %1, off sc0 sc1"
                 :: "v"(p), "v"(v) : "memory");
}
__device__ __forceinline__ void st_u16_wt(unsigned short* p, int v) {
    asm volatile("global_store_short %0, %1, off sc0 sc1"
                 :: "v"(p), "v"(v) : "memory");
}
__device__ __forceinline__ int ld_cg(const int* p) {
    int r;
    asm volatile("global_load_dword %0, %1, off sc0 sc1\n\t"
                 "s_waitcnt vmcnt(0)"
                 : "=v"(r) : "v"(p) : "memory");
    return r;
}
__device__ __forceinline__ void ld_cg4(const int* p0, const int* p1,
                                       const int* p2, const int* p3,
                                       int& r0, int& r1, int& r2, int& r3) {
    asm volatile("global_load_dword %0, %4, off sc0 sc1\n\t"
                 "global_load_dword %1, %5, off sc0 sc1\n\t"
                 "global_load_dword %2, %6, off sc0 sc1\n\t"
                 "global_load_dword %3, %7, off sc0 sc1\n\t"
                 "s_waitcnt vmcnt(0)"
                 : "=&v"(r0), "=&v"(r1), "=&v"(r2), "=&v"(r3)
                 : "v"(p0), "v"(p1), "v"(p2), "v"(p3) : "memory");
}

// ---------------------------------------------------------------------------
// 2-level tree grid barrier (r23-proven, ~1-2us), templated on group size.
// Valid: all blocks co-resident AND cross-block data write-once + WT
// (vmcnt(0) drain = data at coherence point before arrival). SPINCAP makes
// a broken barrier fail the absmax check within ~0.5s, not hang/timeout.
// ---------------------------------------------------------------------------
template <int GSZT>
__device__ __forceinline__ void tree_barrier(int* __restrict__ bar, int b) {
    asm volatile("s_waitcnt vmcnt(0) lgkmcnt(0)" ::: "memory");
    __syncthreads();
    if (threadIdx.x == 0) {
        int* grp  = bar + (b * CPB + ((int)blockIdx.x & (NGRP - 1))) * CSTRIDE;
        int* root = bar + (b * CPB + NGRP) * CSTRIDE;
        const int a = __hip_atomic_fetch_add(grp, 1, __ATOMIC_RELAXED,
                                             __HIP_MEMORY_SCOPE_AGENT);
        if (a == GSZT - 1)
            __hip_atomic_fetch_add(root, 1, __ATOMIC_RELAXED,
                                   __HIP_MEMORY_SCOPE_AGENT);
        int spin = 0;
        while (__hip_atomic_load(root, __ATOMIC_RELAXED,
                                 __HIP_MEMORY_SCOPE_AGENT) < NGRP) {
            __builtin_amdgcn_s_sleep(2);
            if (++spin > SPINCAP) break;          // failsafe: fail visibly
        }
    }
    __syncthreads();
}

// ---------------------------------------------------------------------------
// Register-resident top-9 (smallest d2).
// ---------------------------------------------------------------------------
struct TopK {
    float d[KNB];
    int   id[KNB];
    float dw;

    __device__ __forceinline__ void init() {
#pragma unroll
        for (int s = 0; s < KNB; ++s) { d[s] = FBIG; id[s] = -1; }
        dw = FBIG;
    }
    __device__ __forceinline__ void push(float d2, int j) {
        if (d2 < dw) {
            bool done = false;
#pragma unroll
            for (int s = 0; s < KNB; ++s) {
                bool m = (!done) && (d[s] == dw);
                d[s]  = m ? d2 : d[s];
                id[s] = m ? j  : id[s];
                done  = done || m;
            }
            float m0 = fmaxf(fmaxf(d[0], d[1]), d[2]);
            float m1 = fmaxf(fmaxf(d[3], d[4]), d[5]);
            float m2 = fmaxf(fmaxf(d[6], d[7]), d[8]);
            dw = fmaxf(fmaxf(m0, m1), m2);
        }
    }
};

__device__ __forceinline__ int clampG(int c) { return min(G - 1, max(0, c)); }

// ---------------------------------------------------------------------------
// kNN body, 4 lanes per point (r13-proven). Lane-0 slot order broadcast.
// ---------------------------------------------------------------------------
template <bool LDSMODE>
__device__ __forceinline__ void knn_body(int p, int l, float qx, float qy,
                                         int cx, int cy, int ry0, int S,
                                         const float2* __restrict__ sP,
                                         const unsigned short* __restrict__ sSp,
                                         const float2* __restrict__ bxy,
                                         const unsigned short* __restrict__ cs16,
                                         int* __restrict__ nbr) {
    TopK tk; tk.init();

    auto spanAt = [&](int idx) -> int {
        return LDSMODE ? (int)sSp[idx - ry0 * G] : (int)cs16[idx];
    };
    auto getPt = [&](int i) -> float2 {
        return LDSMODE ? sP[i - S] : bxy[i];
    };
    auto scan_span = [&](int s, int e) {
        for (int i = s + l; i < e; i += LPP) {
            const float2 pt = getPt(i);
            const float dx = qx - pt.x;
            const float dy = qy - pt.y;
            tk.push(fmaf(dx, dx, dy * dy), i);
        }
    };
    auto row_span = [&](int y, int x0, int x1) {
        if (y < 0 || y >= G) return;
        x0 = max(x0, 0); x1 = min(x1, G - 1);
        if (x0 > x1) return;
        scan_span(spanAt(y * G + x0), spanAt(y * G + x1 + 1));
    };

    row_span(cy - 1, cx - 1, cx + 1);
    row_span(cy,     cx - 1, cx + 1);
    row_span(cy + 1, cx - 1, cx + 1);

    int r = 1;
    while (true) {
        const float dl = (cx - r >= 0) ? fmaxf(qx - (GMIN + (float)(cx - r) * CW), 0.0f) : FBIG;
        const float dr = (cx + r <  G) ? fmaxf((GMIN + (float)(cx + r + 1) * CW) - qx, 0.0f) : FBIG;
        const float db = (cy - r >= 0) ? fmaxf(qy - (GMIN + (float)(cy - r) * CW), 0.0f) : FBIG;
        const float dt = (cy + r <  G) ? fmaxf((GMIN + (float)(cy + r + 1) * CW) - qy, 0.0f) : FBIG;
        const float dmin = fminf(fminf(dl, dr), fminf(db, dt));

        float ub = tk.dw;
        ub = fminf(ub, __shfl_xor(ub, 1));
        ub = fminf(ub, __shfl_xor(ub, 2));
        if (ub < FBIG && ub <= dmin * dmin) break;
        if (r == RCAP) break;                 // keep provisional best-9
        ++r;
        row_span(cy - r, cx - r, cx + r);
        row_span(cy + r, cx - r, cx + r);
        for (int y = cy - r + 1; y <= cy + r - 1; ++y) {
            if (y < 0 || y >= G) continue;
            if (cx - r >= 0) scan_span(spanAt(y * G + cx - r), spanAt(y * G + cx - r + 1));
            if (cx + r <  G) scan_span(spanAt(y * G + cx + r), spanAt(y * G + cx + r + 1));
        }
    }

#pragma unroll
    for (int m = 1; m < LPP; m <<= 1) {
        float od[KNB]; int oid[KNB];
#pragma unroll
        for (int s = 0; s < KNB; ++s) {
            od[s]  = __shfl_xor(tk.d[s], m);
            oid[s] = __shfl_xor(tk.id[s], m);
        }
#pragma unroll
        for (int s = 0; s < KNB; ++s) {
            if (oid[s] >= 0) tk.push(od[s], oid[s]);
        }
    }

#pragma unroll
    for (int s = 0; s < KNB; ++s) {
        const int v = __shfl(tk.id[s], 0, LPP);
        nbr[s] = (v < 0) ? p : v;
    }
}

// ---------------------------------------------------------------------------
// GCN layer (device fn), 8 threads per point with SPLIT gather: lane l
// loads neighbors k%8==l (9 rows loaded once per point), partial aggs
// combined via __shfl_xor butterfly (reassociates the 9-way sum — bounded
// fp32 drift, threshold 9.9e-2). Each lane then computes COUT/8 outputs.
// ---------------------------------------------------------------------------
template <int CIN, int COUT, bool RELU, bool FINAL, bool SCATTER, bool WT>
__device__ __forceinline__ void gcn_dev8(int n, int l, const int* __restrict__ nbr,
                                         const float* __restrict__ hin,
                                         const float* __restrict__ W,
                                         const float* __restrict__ xres,
                                         const int* __restrict__ bid,
                                         float* __restrict__ hout) {
    constexpr int OL = COUT / TPP2;        // outputs per lane (4 or 2)
    static_assert(OL == 4 || OL == 2, "store width");

    float agg[CIN];
#pragma unroll
    for (int c = 0; c < CIN; ++c) agg[c] = 0.0f;

    // lane l loads neighbors k = l, l+8 (lane 0 gets 2 rows, others 1)
    for (int k = l; k < KNB; k += TPP2) {
        const int j = nbr[k];
        const float4* r = reinterpret_cast<const float4*>(hin + (size_t)j * CIN);
#pragma unroll
        for (int c4 = 0; c4 < CIN / 4; ++c4) {
            const float4 v = r[c4];
            agg[4 * c4 + 0] += v.x;
            agg[4 * c4 + 1] += v.y;
            agg[4 * c4 + 2] += v.z;
            agg[4 * c4 + 3] += v.w;
        }
    }

    // butterfly combine of the 8 disjoint partial aggs (octet-local)
#pragma unroll
    for (int m = 1; m < TPP2; m <<= 1) {
#pragma unroll
        for (int c = 0; c < CIN; ++c) agg[c] += __shfl_xor(agg[c], m);
    }
#pragma unroll
    for (int c = 0; c < CIN; ++c) agg[c] *= (1.0f / 9.0f);

    const int outrow = SCATTER ? bid[n] : n;
    const int ob = l * OL;

    float res[OL];
#pragma unroll
    for (int o = 0; o < OL; ++o) {
        float acc = 0.0f;
#pragma unroll
        for (int c = 0; c < CIN; ++c) acc = fmaf(agg[c], W[c * COUT + ob + o], acc);
        if (RELU)  acc = fmaxf(acc, 0.0f);
        if (FINAL) acc = xres[n * COUT + ob + o] + 1e-4f * acc;
        res[o] = acc;
    }

    float* dst = hout + (size_t)outrow * COUT + ob;
    if (OL == 4) {
        const float4 v = make_float4(res[0], res[1], res[OL > 2 ? 2 : 0], res[OL > 2 ? 3 : 1]);
        if (WT) stq_wt(dst, v);
        else    *reinterpret_cast<float4*>(dst) = v;
    } else {
        const float2 v = make_float2(res[0], res[1]);
        if (WT) st2_wt(dst, v);
        else    *reinterpret_cast<float2*>(dst) = v;
    }
}

// ---------------------------------------------------------------------------
// FRONT kernel (unchanged from r28): hist -> scan -> scan -> scatter -> knn;
// writes nb (WT). 256 blocks x 256 threads, 1 block/CU (50KB LDS).
// ---------------------------------------------------------------------------
__global__ __launch_bounds__(KTHR) void mega_front(
        const float* __restrict__ x,
        int* __restrict__ hist,
        int* __restrict__ btot,
        int* __restrict__ cursor,
        float2* __restrict__ bxy,
        int* __restrict__ bid,
        float* __restrict__ xb,
        unsigned short* __restrict__ cs16,
        int* __restrict__ nb,
        int* __restrict__ bar) {
    __shared__ float2 sP[CAPN];                          // 40 KB
    __shared__ uint   sSpU[(ROWSCAP * G) / 2 + 2];       // ~10 KB
    __shared__ int    info[4];
    unsigned short* sSp = reinterpret_cast<unsigned short*>(sSpU);

    const int blk = swz_bid((int)blockIdx.x);            // XCD-local slab id

    // ---- phase A: histogram (swizzled point slab) ----
    if (threadIdx.x < PPB) {
        const int i = blk * PPB + threadIdx.x;
        const float2 pxy = *reinterpret_cast<const float2*>(x + (size_t)i * CDIM);
        const int hx = clampG((int)((pxy.x - GMIN) * INVW));
        const int hy = clampG((int)((pxy.y - GMIN) * INVW));
        atomicAdd(&hist[hy * G + hx], 1);
    }
    tree_barrier<NBLK / NGRP>(bar, 0);

    // ---- phase B: per-block scan of its 64 cells (RAW bid) ----
    int exclLoc = 0;
    if (threadIdx.x < 64) {
        const int c = (int)blockIdx.x * 64 + (int)threadIdx.x;
        const int n = ld_cg(&hist[c]);
        int inc = n;
#pragma unroll
        for (int o = 1; o < 64; o <<= 1) {
            const int v = __shfl_up(inc, o);
            if ((int)threadIdx.x >= o) inc += v;
        }
        exclLoc = inc - n;
        if (threadIdx.x == 63) st1_wt(&btot[blockIdx.x], inc);
    }
    tree_barrier<NBLK / NGRP>(bar, 1);

    // ---- phase C: block offset + write spans (RAW bid) ----
    if (threadIdx.x < 64) {
        const int t = (int)threadIdx.x;
        int v0, v1, v2, v3;
        ld_cg4(&btot[t], &btot[t + 64], &btot[t + 128], &btot[t + 192],
               v0, v1, v2, v3);
        int part = 0;
        if (t       < (int)blockIdx.x) part += v0;
        if (t + 64  < (int)blockIdx.x) part += v1;
        if (t + 128 < (int)blockIdx.x) part += v2;
        if (t + 192 < (int)blockIdx.x) part += v3;
#pragma unroll
        for (int m = 1; m < 64; m <<= 1) part += __shfl_xor(part, m);
        const int c = (int)blockIdx.x * 64 + t;
        const int e = part + exclLoc;
        st1_wt(&cursor[c], e);
        st_u16_wt(&cs16[c], e);
        if (blockIdx.x == 0 && t == 0)
            st1_wt(reinterpret_cast<int*>(cs16 + GC),
                   (int)(NPTS | (NPTS << 16)));
    }
    tree_barrier<NBLK / NGRP>(bar, 2);

    // ---- phase D: scatter into binned order (swizzled) ----
    if (threadIdx.x < PPB) {
        const int i = blk * PPB + threadIdx.x;
        const float4* src = reinterpret_cast<const float4*>(x + (size_t)i * CDIM);
        const float4 v0 = src[0];
        const int cx = clampG((int)((v0.x - GMIN) * INVW));
        const int cy = clampG((int)((v0.y - GMIN) * INVW));
        const int pos = atomicAdd(&cursor[cy * G + cx], 1);
        float* dst = xb + (size_t)pos * CDIM;
        stq_wt(dst + 0,  v0);
        stq_wt(dst + 4,  src[1]);
        stq_wt(dst + 8,  src[2]);
        stq_wt(dst + 12, src[3]);
        st2_wt(reinterpret_cast<float*>(&bxy[pos]), make_float2(v0.x, v0.y));
        st1_wt(&bid[pos], i);
    }
    tree_barrier<NBLK / NGRP>(bar, 3);

    // ---- phase E: kNN ----
    const int g = threadIdx.x >> 2;
    const int l = threadIdx.x & (LPP - 1);
    const int p = blk * PPB + g;

    if (threadIdx.x == 0) {
        const float2 qa = bxy[blk * PPB];
        const float2 qb = bxy[blk * PPB + PPB - 1];
        const int cya = clampG((int)((qa.y - GMIN) * INVW));
        const int cyb = clampG((int)((qb.y - GMIN) * INVW));
        const int ry0 = max(0, cya - RCAP);
        const int ry1 = min(G - 1, cyb + RCAP);
        info[0] = ry0;
        info[1] = ry1;
        info[2] = (int)cs16[ry0 * G];
        info[3] = (int)cs16[(ry1 + 1) * G];
    }
    __syncthreads();
    const int ry0 = info[0], ry1 = info[1], S = info[2], E = info[3];
    const int nrows = ry1 - ry0 + 1;
    const bool useLDS = ((E - S) <= CAPN) && (nrows <= ROWSCAP);

    if (useLDS) {
        const int nspan = nrows * G + 1;
        const uint* gsp = reinterpret_cast<const uint*>(cs16 + ry0 * G);
        for (int t = threadIdx.x; t < nspan / 2; t += KTHR) sSpU[t] = gsp[t];
        if (threadIdx.x == 0) sSp[nspan - 1] = cs16[ry0 * G + nspan - 1];
        for (int t = threadIdx.x; t < E - S; t += KTHR) sP[t] = bxy[S + t];
    }
    __syncthreads();

    const float2 q = bxy[p];
    const int cx = clampG((int)((q.x - GMIN) * INVW));
    const int cy = clampG((int)((q.y - GMIN) * INVW));

    int nbr[KNB];
    if (useLDS) knn_body<true >(p, l, q.x, q.y, cx, cy, ry0, S, sP, sSp, bxy, cs16, nbr);
    else        knn_body<false>(p, l, q.x, q.y, cx, cy, ry0, S, sP, sSp, bxy, cs16, nbr);

    if (l == 0) {
#pragma unroll
        for (int s = 0; s < KNB; ++s) st1_wt(&nb[p * KNB + s], nbr[s]);
    }
}

// ---------------------------------------------------------------------------
// GCN kernel: 512 blocks x 256 threads, 2 blocks/CU (launch_bounds-pinned),
// TPP2=8 split gather. 8 layers under tree barriers 0-6 on bar2 (groups of
// 32). Reads nb (fresh caches after dispatch boundary). No LDS.
// ---------------------------------------------------------------------------
__global__ __launch_bounds__(KTHR, 2) void mega_gcn(
        const int* __restrict__ nb,
        const int* __restrict__ bid,
        const float* __restrict__ xb,
        const float* __restrict__ W1, const float* __restrict__ W2,
        const float* __restrict__ W3, const float* __restrict__ W4,
        float* __restrict__ xb1,
        float* __restrict__ hA0, float* __restrict__ hB0, float* __restrict__ hC0,
        float* __restrict__ hA1, float* __restrict__ hB1, float* __restrict__ hC1,
        float* __restrict__ out,
        int* __restrict__ bar2) {
    const int blk = swz_bid2((int)blockIdx.x);
    const int g = threadIdx.x >> 3;          // octet index (0..31)
    const int l = threadIdx.x & (TPP2 - 1);  // lane in octet
    const int p = blk * PPB2 + g;

    int nbr[KNB];
#pragma unroll
    for (int s = 0; s < KNB; ++s) nbr[s] = nb[p * KNB + s];

    // step 0 (binned in -> binned out)
    gcn_dev8<CDIM, HDIM, true,  false, false, true >(p, l, nbr, xb,  W1, nullptr, nullptr, hA0);
    tree_barrier<NBLK2 / NGRP>(bar2, 0);
    gcn_dev8<HDIM, HDIM, true,  false, false, true >(p, l, nbr, hA0, W2, nullptr, nullptr, hB0);
    tree_barrier<NBLK2 / NGRP>(bar2, 1);
    gcn_dev8<HDIM, HDIM, true,  false, false, true >(p, l, nbr, hB0, W3, nullptr, nullptr, hC0);
    tree_barrier<NBLK2 / NGRP>(bar2, 2);
    gcn_dev8<HDIM, CDIM, false, true,  false, true >(p, l, nbr, hC0, W4, xb, nullptr, xb1);
    tree_barrier<NBLK2 / NGRP>(bar2, 3);
    // step 1 (binned in -> original order out)
    gcn_dev8<CDIM, HDIM, true,  false, false, true >(p, l, nbr, xb1, W1, nullptr, nullptr, hA1);
    tree_barrier<NBLK2 / NGRP>(bar2, 4);
    gcn_dev8<HDIM, HDIM, true,  false, false, true >(p, l, nbr, hA1, W2, nullptr, nullptr, hB1);
    tree_barrier<NBLK2 / NGRP>(bar2, 5);
    gcn_dev8<HDIM, HDIM, true,  false, false, true >(p, l, nbr, hB1, W3, nullptr, nullptr, hC1);
    tree_barrier<NBLK2 / NGRP>(bar2, 6);
    gcn_dev8<HDIM, CDIM, false, true,  true,  false>(p, l, nbr, hC1, W4, xb1, bid, out);
}

// ---------------------------------------------------------------------------
// 3 nodes: memset (hist+bar+bar2) + mega_front(256) + mega_gcn(512).
// ---------------------------------------------------------------------------
extern "C" void kernel_launch(void* const* d_in, const int* in_sizes, int n_in,
                              void* d_out, int out_size, void* d_ws, size_t ws_size,
                              hipStream_t stream) {
    const float* seed = (const float*)d_in[0];
    const float* W1   = (const float*)d_in[1];
    const float* W2   = (const float*)d_in[2];
    const float* W3   = (const float*)d_in[3];
    const float* W4   = (const float*)d_in[4];
    float* out = (float*)d_out;

    char* ws = (char*)d_ws;
    size_t off = 0;
    auto alloc = [&](size_t bytes) -> void* {
        void* p = ws + off;
        off += (bytes + 255) & ~(size_t)255;
        return p;
    };
    unsigned short* cs16   = (unsigned short*)alloc((GC + 16) * sizeof(unsigned short));
    int*            cursor = (int*)   alloc(GC * sizeof(int));
    float2*         bxy    = (float2*)alloc((size_t)NPTS * sizeof(float2));
    int*            bid    = (int*)   alloc(NPTS * sizeof(int));
    float*          xb     = (float*) alloc((size_t)NPTS * CDIM * sizeof(float));
    float*          xb1    = (float*) alloc((size_t)NPTS * CDIM * sizeof(float));
    float*          hA0    = (float*) alloc((size_t)NPTS * HDIM * sizeof(float));
    float*          hB0    = (float*) alloc((size_t)NPTS * HDIM * sizeof(float));
    float*          hC0    = (float*) alloc((size_t)NPTS * HDIM * sizeof(float));
    float*          hA1    = (float*) alloc((size_t)NPTS * HDIM * sizeof(float));
    float*          hB1    = (float*) alloc((size_t)NPTS * HDIM * sizeof(float));
    float*          hC1    = (float*) alloc((size_t)NPTS * HDIM * sizeof(float));
    int*            nb     = (int*)   alloc((size_t)NPTS * KNB * sizeof(int));
    // hist, bar, bar2 ADJACENT so one memset zeroes all three.
    int*            hist   = (int*)   alloc(GC * sizeof(int));
    int*            bar    = (int*)   alloc(BARINTS * sizeof(int));
    int*            bar2   = (int*)   alloc(BARINTS2 * sizeof(int));
    int*            btot   = (int*)   alloc(NBLK * sizeof(int));

    const size_t zbytes = (size_t)((char*)bar2 + BARINTS2 * sizeof(int) - (char*)hist);
    hipMemsetAsync(hist, 0, zbytes, stream);

    mega_front<<<NBLK,  KTHR, 0, stream>>>(seed, hist, btot, cursor, bxy, bid,
                                           xb, cs16, nb, bar);
    mega_gcn  <<<NBLK2, KTHR, 0, stream>>>(nb, bid, xb, W1, W2, W3, W4, xb1,
                                           hA0, hB0, hC0, hA1, hB1, hC1,
                                           out, bar2);
}

// Round 15
// 162.603 us; speedup vs baseline: 1.0818x; 1.0818x over previous
//
#include <hip/hip_runtime.h>

// r31 = r27 VERBATIM — the session-best (measured 162.7us), resubmitted as
// FINAL per r30's pre-declared decision rule (gcn>=50us AND total>=163
// both fired: occupancy 10.8->21.7% yet gcn 56.5->66.0us — TLP hypothesis
// refuted for the third and final time).
// Final accounting: ~64us fixed harness overhead (constant r20-r28) +
// ~100us mega (11us VALU, 16-20us barriers, rest distributed gather
// latency). Refuted levers: device-fence protocols (r18/r25, big
// regressions), TLP x3 (r21/r29/r30), gather ILP (r26 null), XCD swizzle
// (r27: FETCH 20.2->9.6MB, time unchanged -> not fetch-bound).
// Structure: memset + ONE fused kernel (hist/scan/scatter/knn/8xGCN) under
// r23's tree barriers, r24's WT write-once protocol, r27's XCD swizzle.

// Problem constants (fixed by setup_inputs)
constexpr int NPTS = 16384;
constexpr int KNB  = 9;
constexpr int CDIM = 16;
constexpr int HDIM = 32;

// Spatial grid: FIXED bounds (data ~ N(0,1)). Outliers clamp into edge cells;
// search stays EXACT for converged points.
constexpr int   G    = 128;
constexpr int   GC   = G * G;
constexpr float GMIN = -3.3f;
constexpr float GMAX =  3.3f;
constexpr float CW   = (GMAX - GMIN) / G;
constexpr float INVW = G / (GMAX - GMIN);
constexpr float FBIG = 3.0e38f;

// Ring cap (r12/r13 measured absmax 0.0078 vs threshold 9.9e-2).
constexpr int RCAP = 5;

// Fused-kernel geometry: 4 lanes per point. 256 blocks x 256 threads
// (65536 threads -> all 256 CUs, 4 waves/CU). 64 points per block.
constexpr int LPP     = 4;
constexpr int KTHR    = 256;             // threads per block
constexpr int PPB     = KTHR / LPP;      // 64 points per block
constexpr int NBLK    = NPTS / PPB;      // 256 blocks == CU count
constexpr int CAPN    = 5120;            // max staged candidates (40 KB)
constexpr int ROWSCAP = 40;              // max staged cell rows (~10 KB)

// Tree-barrier geometry: 16 groups x 16 blocks; counters padded to 128B.
constexpr int NGRP    = 16;              // groups per barrier
constexpr int GSZ     = NBLK / NGRP;     // 16 blocks per group
constexpr int CSTRIDE = 32;              // ints per counter line (128 B)
constexpr int NBARS   = 11;              // 3 span-build + scatter + 7 gcn
constexpr int CPB     = NGRP + 1;        // counters per barrier (groups+root)
constexpr int BARINTS = NBARS * CPB * CSTRIDE;   // total ints (~24 KB)

// Bijective XCD swizzle: XCD k (bid%8==k under round-robin) gets slabs
// [32k, 32k+32) — a contiguous 2048-point binned range per XCD.
__device__ __forceinline__ int swz_bid(int b) { return (b & 7) * (NBLK / 8) + (b >> 3); }

// ---------------------------------------------------------------------------
// Write-through stores (sc0 sc1: through L1+L2 to the coherence point) and
// coherent loads (sc0 sc1) for lines written by atomics/WT inside THIS
// launch. ext_vector payloads map to VGPR tuples for "v" constraints.
// ---------------------------------------------------------------------------
typedef float f32x4_t __attribute__((ext_vector_type(4)));
typedef float f32x2_t __attribute__((ext_vector_type(2)));

__device__ __forceinline__ void stq_wt(float* p, float4 v) {
    f32x4_t w; w.x = v.x; w.y = v.y; w.z = v.z; w.w = v.w;
    asm volatile("global_store_dwordx4 %0, %1, off sc0 sc1"
                 :: "v"(p), "v"(w) : "memory");
}
__device__ __forceinline__ void st2_wt(float* p, float2 v) {
    f32x2_t w; w.x = v.x; w.y = v.y;
    asm volatile("global_store_dwordx2 %0, %1, off sc0 sc1"
                 :: "v"(p), "v"(w) : "memory");
}
__device__ __forceinline__ void st1_wt(int* p, int v) {
    asm volatile("global_store_dword %0, %1, off sc0 sc1"
                 :: "v"(p), "v"(v) : "memory");
}
__device__ __forceinline__ void st_u16_wt(unsigned short* p, int v) {
    asm volatile("global_store_short %0, %1, off sc0 sc1"
                 :: "v"(p), "v"(v) : "memory");
}
__device__ __forceinline__ int ld_cg(const int* p) {
    int r;
    asm volatile("global_load_dword %0, %1, off sc0 sc1\n\t"
                 "s_waitcnt vmcnt(0)"
                 : "=v"(r) : "v"(p) : "memory");
    return r;
}
__device__ __forceinline__ void ld_cg4(const int* p0, const int* p1,
                                       const int* p2, const int* p3,
                                       int& r0, int& r1, int& r2, int& r3) {
    asm volatile("global_load_dword %0, %4, off sc0 sc1\n\t"
                 "global_load_dword %1, %5, off sc0 sc1\n\t"
                 "global_load_dword %2, %6, off sc0 sc1\n\t"
                 "global_load_dword %3, %7, off sc0 sc1\n\t"
                 "s_waitcnt vmcnt(0)"
                 : "=&v"(r0), "=&v"(r1), "=&v"(r2), "=&v"(r3)
                 : "v"(p0), "v"(p1), "v"(p2), "v"(p3) : "memory");
}

// ---------------------------------------------------------------------------
// 2-level tree grid barrier (r23-proven, ~1-2us). Valid ONLY because all 256
// blocks are co-resident (1 block/CU) AND cross-block data is write-once +
// write-through (vmcnt(0) drain = data at coherence point before arrival).
// Failsafe spin cap: a broken barrier fails the absmax check, not a hang.
// ---------------------------------------------------------------------------
__device__ __forceinline__ void tree_barrier(int* __restrict__ bar, int b) {
    asm volatile("s_waitcnt vmcnt(0) lgkmcnt(0)" ::: "memory");
    __syncthreads();
    if (threadIdx.x == 0) {
        int* grp  = bar + (b * CPB + ((int)blockIdx.x & (NGRP - 1))) * CSTRIDE;
        int* root = bar + (b * CPB + NGRP) * CSTRIDE;
        const int a = __hip_atomic_fetch_add(grp, 1, __ATOMIC_RELAXED,
                                             __HIP_MEMORY_SCOPE_AGENT);
        if (a == GSZ - 1)
            __hip_atomic_fetch_add(root, 1, __ATOMIC_RELAXED,
                                   __HIP_MEMORY_SCOPE_AGENT);
        int spin = 0;
        while (__hip_atomic_load(root, __ATOMIC_RELAXED,
                                 __HIP_MEMORY_SCOPE_AGENT) < NGRP) {
            __builtin_amdgcn_s_sleep(2);
            if (++spin > (1 << 22)) break;        // failsafe: fail visibly
        }
    }
    __syncthreads();
}

// ---------------------------------------------------------------------------
// Register-resident top-9 (smallest d2).
// ---------------------------------------------------------------------------
struct TopK {
    float d[KNB];
    int   id[KNB];
    float dw;

    __device__ __forceinline__ void init() {
#pragma unroll
        for (int s = 0; s < KNB; ++s) { d[s] = FBIG; id[s] = -1; }
        dw = FBIG;
    }
    __device__ __forceinline__ void push(float d2, int j) {
        if (d2 < dw) {
            bool done = false;
#pragma unroll
            for (int s = 0; s < KNB; ++s) {
                bool m = (!done) && (d[s] == dw);
                d[s]  = m ? d2 : d[s];
                id[s] = m ? j  : id[s];
                done  = done || m;
            }
            float m0 = fmaxf(fmaxf(d[0], d[1]), d[2]);
            float m1 = fmaxf(fmaxf(d[3], d[4]), d[5]);
            float m2 = fmaxf(fmaxf(d[6], d[7]), d[8]);
            dw = fmaxf(fmaxf(m0, m1), m2);
        }
    }
};

__device__ __forceinline__ int clampG(int c) { return min(G - 1, max(0, c)); }

// ---------------------------------------------------------------------------
// kNN body, 4 lanes per point (r13-proven search; result in registers,
// lane-0 slot order broadcast via __shfl(v,0,4) — matches r17's nb).
// ---------------------------------------------------------------------------
template <bool LDSMODE>
__device__ __forceinline__ void knn_body(int p, int l, float qx, float qy,
                                         int cx, int cy, int ry0, int S,
                                         const float2* __restrict__ sP,
                                         const unsigned short* __restrict__ sSp,
                                         const float2* __restrict__ bxy,
                                         const unsigned short* __restrict__ cs16,
                                         int* __restrict__ nbr) {
    TopK tk; tk.init();

    auto spanAt = [&](int idx) -> int {
        return LDSMODE ? (int)sSp[idx - ry0 * G] : (int)cs16[idx];
    };
    auto getPt = [&](int i) -> float2 {
        return LDSMODE ? sP[i - S] : bxy[i];
    };
    auto scan_span = [&](int s, int e) {
        for (int i = s + l; i < e; i += LPP) {
            const float2 pt = getPt(i);
            const float dx = qx - pt.x;
            const float dy = qy - pt.y;
            tk.push(fmaf(dx, dx, dy * dy), i);
        }
    };
    auto row_span = [&](int y, int x0, int x1) {
        if (y < 0 || y >= G) return;
        x0 = max(x0, 0); x1 = min(x1, G - 1);
        if (x0 > x1) return;
        scan_span(spanAt(y * G + x0), spanAt(y * G + x1 + 1));
    };

    row_span(cy - 1, cx - 1, cx + 1);
    row_span(cy,     cx - 1, cx + 1);
    row_span(cy + 1, cx - 1, cx + 1);

    int r = 1;
    while (true) {
        const float dl = (cx - r >= 0) ? fmaxf(qx - (GMIN + (float)(cx - r) * CW), 0.0f) : FBIG;
        const float dr = (cx + r <  G) ? fmaxf((GMIN + (float)(cx + r + 1) * CW) - qx, 0.0f) : FBIG;
        const float db = (cy - r >= 0) ? fmaxf(qy - (GMIN + (float)(cy - r) * CW), 0.0f) : FBIG;
        const float dt = (cy + r <  G) ? fmaxf((GMIN + (float)(cy + r + 1) * CW) - qy, 0.0f) : FBIG;
        const float dmin = fminf(fminf(dl, dr), fminf(db, dt));

        // quad-wide valid upper bound on the union's 9th-best
        float ub = tk.dw;
        ub = fminf(ub, __shfl_xor(ub, 1));
        ub = fminf(ub, __shfl_xor(ub, 2));
        if (ub < FBIG && ub <= dmin * dmin) break;
        if (r == RCAP) break;                 // keep provisional best-9
        ++r;
        row_span(cy - r, cx - r, cx + r);
        row_span(cy + r, cx - r, cx + r);
        for (int y = cy - r + 1; y <= cy + r - 1; ++y) {
            if (y < 0 || y >= G) continue;
            if (cx - r >= 0) scan_span(spanAt(y * G + cx - r), spanAt(y * G + cx - r + 1));
            if (cx + r <  G) scan_span(spanAt(y * G + cx + r), spanAt(y * G + cx + r + 1));
        }
    }

    // Butterfly merge of the 4 disjoint partial top-9 lists (quad-local).
#pragma unroll
    for (int m = 1; m < LPP; m <<= 1) {
        float od[KNB]; int oid[KNB];
#pragma unroll
        for (int s = 0; s < KNB; ++s) {
            od[s]  = __shfl_xor(tk.d[s], m);
            oid[s] = __shfl_xor(tk.id[s], m);
        }
#pragma unroll
        for (int s = 0; s < KNB; ++s) {
            if (oid[s] >= 0) tk.push(od[s], oid[s]);
        }
    }

    // Broadcast lane 0's merged list (slot ORDER matches r17's nb).
    // Self-fill any unfilled slots so gather indices stay in-bounds.
#pragma unroll
    for (int s = 0; s < KNB; ++s) {
        const int v = __shfl(tk.id[s], 0, LPP);
        nbr[s] = (v < 0) ? p : v;
    }
}

// ---------------------------------------------------------------------------
// GCN layer (device fn), 4 threads per point (r24-proven form). Gathers are
// NORMAL cached loads; outputs write-through. Bitwise-identical math to r17.
// ---------------------------------------------------------------------------
template <int CIN, int COUT, bool RELU, bool FINAL, bool SCATTER, bool WT>
__device__ __forceinline__ void gcn_dev(int n, int l, const int* __restrict__ nbr,
                                        const float* __restrict__ hin,
                                        const float* __restrict__ W,
                                        const float* __restrict__ xres,
                                        const int* __restrict__ bid,
                                        float* __restrict__ hout) {
    constexpr int OL = COUT / LPP;         // outputs per lane (8 or 4)
    static_assert(OL % 4 == 0, "float4 store");

    float agg[CIN];
#pragma unroll
    for (int c = 0; c < CIN; ++c) agg[c] = 0.0f;

#pragma unroll
    for (int k = 0; k < KNB; ++k) {
        const int j = nbr[k];
        const float4* r = reinterpret_cast<const float4*>(hin + (size_t)j * CIN);
#pragma unroll
        for (int c4 = 0; c4 < CIN / 4; ++c4) {
            const float4 v = r[c4];
            agg[4 * c4 + 0] += v.x;
            agg[4 * c4 + 1] += v.y;
            agg[4 * c4 + 2] += v.z;
            agg[4 * c4 + 3] += v.w;
        }
    }
#pragma unroll
    for (int c = 0; c < CIN; ++c) agg[c] *= (1.0f / 9.0f);

    const int outrow = SCATTER ? bid[n] : n;
    const int ob = l * OL;

    float res[OL];
#pragma unroll
    for (int o = 0; o < OL; ++o) {
        float acc = 0.0f;
#pragma unroll
        for (int c = 0; c < CIN; ++c) acc = fmaf(agg[c], W[c * COUT + ob + o], acc);
        if (RELU)  acc = fmaxf(acc, 0.0f);
        if (FINAL) acc = xres[n * COUT + ob + o] + 1e-4f * acc;
        res[o] = acc;
    }

    float* dst = hout + (size_t)outrow * COUT + ob;
#pragma unroll
    for (int o4 = 0; o4 < OL / 4; ++o4) {
        const float4 v = make_float4(res[4 * o4 + 0], res[4 * o4 + 1],
                                     res[4 * o4 + 2], res[4 * o4 + 3]);
        if (WT) stq_wt(dst + 4 * o4, v);
        else    *reinterpret_cast<float4*>(dst + 4 * o4) = v;
    }
}

// ---------------------------------------------------------------------------
// Mega kernel: hist -> scan(2-level) -> scatter -> knn (ids in registers)
// -> gcn x8, all under tree grid barriers. Point-indexed phases use the
// XCD-swizzled slab id `blk`; cell-scan phases B/C use raw blockIdx.x.
// hist pre-zeroed by a memset node. 256 blocks x 256 threads, 1 block/CU.
// ---------------------------------------------------------------------------
__global__ __launch_bounds__(KTHR) void mega_kernel(
        const float* __restrict__ x,
        int* __restrict__ hist,
        int* __restrict__ btot,
        int* __restrict__ cursor,
        float2* __restrict__ bxy,
        int* __restrict__ bid,
        float* __restrict__ xb,
        unsigned short* __restrict__ cs16,
        const float* __restrict__ W1, const float* __restrict__ W2,
        const float* __restrict__ W3, const float* __restrict__ W4,
        float* __restrict__ xb1,
        float* __restrict__ hA0, float* __restrict__ hB0, float* __restrict__ hC0,
        float* __restrict__ hA1, float* __restrict__ hB1, float* __restrict__ hC1,
        float* __restrict__ out,
        int* __restrict__ bar) {
    __shared__ float2 sP[CAPN];                          // 40 KB
    __shared__ uint   sSpU[(ROWSCAP * G) / 2 + 2];       // ~10 KB
    __shared__ int    info[4];
    unsigned short* sSp = reinterpret_cast<unsigned short*>(sSpU);

    const int blk = swz_bid((int)blockIdx.x);            // XCD-local slab id

    // ---- phase A: histogram (64 points/block, global coherence-point RMW) --
    if (threadIdx.x < PPB) {
        const int i = blk * PPB + threadIdx.x;
        const float2 pxy = *reinterpret_cast<const float2*>(x + (size_t)i * CDIM);
        const int hx = clampG((int)((pxy.x - GMIN) * INVW));
        const int hy = clampG((int)((pxy.y - GMIN) * INVW));
        atomicAdd(&hist[hy * G + hx], 1);
    }
    tree_barrier(bar, 0);

    // ---- phase B: per-block scan of its 64 cells (wave 0 only; RAW bid) ----
    int exclLoc = 0;
    if (threadIdx.x < 64) {
        const int c = (int)blockIdx.x * 64 + (int)threadIdx.x;
        const int n = ld_cg(&hist[c]);          // atomic-written -> coherent load
        int inc = n;
#pragma unroll
        for (int o = 1; o < 64; o <<= 1) {
            const int v = __shfl_up(inc, o);
            if ((int)threadIdx.x >= o) inc += v;
        }
        exclLoc = inc - n;
        if (threadIdx.x == 63) st1_wt(&btot[blockIdx.x], inc);
    }
    tree_barrier(bar, 1);

    // ---- phase C: block offset (redundant reduce) + write spans (RAW bid) --
    if (threadIdx.x < 64) {
        const int t = (int)threadIdx.x;
        int v0, v1, v2, v3;
        ld_cg4(&btot[t], &btot[t + 64], &btot[t + 128], &btot[t + 192],
               v0, v1, v2, v3);
        int part = 0;
        if (t       < (int)blockIdx.x) part += v0;
        if (t + 64  < (int)blockIdx.x) part += v1;
        if (t + 128 < (int)blockIdx.x) part += v2;
        if (t + 192 < (int)blockIdx.x) part += v3;
#pragma unroll
        for (int m = 1; m < 64; m <<= 1) part += __shfl_xor(part, m);
        const int c = (int)blockIdx.x * 64 + t;
        const int e = part + exclLoc;
        st1_wt(&cursor[c], e);
        st_u16_wt(&cs16[c], e);
        if (blockIdx.x == 0 && t == 0)
            st1_wt(reinterpret_cast<int*>(cs16 + GC),
                   (int)(NPTS | (NPTS << 16)));  // cs16[GC]=cs16[GC+1]=NPTS
    }
    tree_barrier(bar, 2);

    // ---- phase D: scatter into binned order (threads 0..63, swizzled) ----
    if (threadIdx.x < PPB) {
        const int i = blk * PPB + threadIdx.x;
        const float4* src = reinterpret_cast<const float4*>(x + (size_t)i * CDIM);
        const float4 v0 = src[0];
        const int cx = clampG((int)((v0.x - GMIN) * INVW));
        const int cy = clampG((int)((v0.y - GMIN) * INVW));
        const int pos = atomicAdd(&cursor[cy * G + cx], 1);
        float* dst = xb + (size_t)pos * CDIM;
        stq_wt(dst + 0,  v0);
        stq_wt(dst + 4,  src[1]);
        stq_wt(dst + 8,  src[2]);
        stq_wt(dst + 12, src[3]);
        st2_wt(reinterpret_cast<float*>(&bxy[pos]), make_float2(v0.x, v0.y));
        st1_wt(&bid[pos], i);
    }
    tree_barrier(bar, 3);

    // ---- phase E: kNN (capped ring, LDS-staged candidate window) ----
    const int g = threadIdx.x >> 2;          // point group within block
    const int l = threadIdx.x & (LPP - 1);   // lane within quad
    const int p = blk * PPB + g;             // point id (binned order)

    if (threadIdx.x == 0) {
        const float2 qa = bxy[blk * PPB];
        const float2 qb = bxy[blk * PPB + PPB - 1];
        const int cya = clampG((int)((qa.y - GMIN) * INVW));
        const int cyb = clampG((int)((qb.y - GMIN) * INVW));
        const int ry0 = max(0, cya - RCAP);
        const int ry1 = min(G - 1, cyb + RCAP);
        info[0] = ry0;
        info[1] = ry1;
        info[2] = (int)cs16[ry0 * G];
        info[3] = (int)cs16[(ry1 + 1) * G];   // ry1==G-1 -> cs16[GC]==NPTS
    }
    __syncthreads();
    const int ry0 = info[0], ry1 = info[1], S = info[2], E = info[3];
    const int nrows = ry1 - ry0 + 1;
    const bool useLDS = ((E - S) <= CAPN) && (nrows <= ROWSCAP);

    if (useLDS) {
        const int nspan = nrows * G + 1;
        const uint* gsp = reinterpret_cast<const uint*>(cs16 + ry0 * G);
        for (int t = threadIdx.x; t < nspan / 2; t += KTHR) sSpU[t] = gsp[t];
        if (threadIdx.x == 0) sSp[nspan - 1] = cs16[ry0 * G + nspan - 1];
        for (int t = threadIdx.x; t < E - S; t += KTHR) sP[t] = bxy[S + t];
    }
    __syncthreads();

    const float2 q = bxy[p];
    const int cx = clampG((int)((q.x - GMIN) * INVW));
    const int cy = clampG((int)((q.y - GMIN) * INVW));

    int nbr[KNB];
    if (useLDS) knn_body<true >(p, l, q.x, q.y, cx, cy, ry0, S, sP, sSp, bxy, cs16, nbr);
    else        knn_body<false>(p, l, q.x, q.y, cx, cy, ry0, S, sP, sSp, bxy, cs16, nbr);

    // ---- phase F: two GCN steps (kNN graph reused; r8-r13 validated) ----
    // step 0 (binned in -> binned out)
    gcn_dev<CDIM, HDIM, true,  false, false, true >(p, l, nbr, xb,  W1, nullptr, nullptr, hA0);
    tree_barrier(bar, 4);
    gcn_dev<HDIM, HDIM, true,  false, false, true >(p, l, nbr, hA0, W2, nullptr, nullptr, hB0);
    tree_barrier(bar, 5);
    gcn_dev<HDIM, HDIM, true,  false, false, true >(p, l, nbr, hB0, W3, nullptr, nullptr, hC0);
    tree_barrier(bar, 6);
    gcn_dev<HDIM, CDIM, false, true,  false, true >(p, l, nbr, hC0, W4, xb, nullptr, xb1);
    tree_barrier(bar, 7);
    // step 1 (binned in -> original order out)
    gcn_dev<CDIM, HDIM, true,  false, false, true >(p, l, nbr, xb1, W1, nullptr, nullptr, hA1);
    tree_barrier(bar, 8);
    gcn_dev<HDIM, HDIM, true,  false, false, true >(p, l, nbr, hA1, W2, nullptr, nullptr, hB1);
    tree_barrier(bar, 9);
    gcn_dev<HDIM, HDIM, true,  false, false, true >(p, l, nbr, hB1, W3, nullptr, nullptr, hC1);
    tree_barrier(bar, 10);
    gcn_dev<HDIM, CDIM, false, true,  true,  false>(p, l, nbr, hC1, W4, xb1, bid, out);
}

// ---------------------------------------------------------------------------
// 1 memset node (hist+bar zero) + 1 kernel node (everything fused).
// ---------------------------------------------------------------------------
extern "C" void kernel_launch(void* const* d_in, const int* in_sizes, int n_in,
                              void* d_out, int out_size, void* d_ws, size_t ws_size,
                              hipStream_t stream) {
    const float* seed = (const float*)d_in[0];
    const float* W1   = (const float*)d_in[1];
    const float* W2   = (const float*)d_in[2];
    const float* W3   = (const float*)d_in[3];
    const float* W4   = (const float*)d_in[4];
    float* out = (float*)d_out;

    char* ws = (char*)d_ws;
    size_t off = 0;
    auto alloc = [&](size_t bytes) -> void* {
        void* p = ws + off;
        off += (bytes + 255) & ~(size_t)255;
        return p;
    };
    unsigned short* cs16   = (unsigned short*)alloc((GC + 16) * sizeof(unsigned short));
    int*            cursor = (int*)   alloc(GC * sizeof(int));
    float2*         bxy    = (float2*)alloc((size_t)NPTS * sizeof(float2));
    int*            bid    = (int*)   alloc(NPTS * sizeof(int));
    float*          xb     = (float*) alloc((size_t)NPTS * CDIM * sizeof(float));
    float*          xb1    = (float*) alloc((size_t)NPTS * CDIM * sizeof(float));
    float*          hA0    = (float*) alloc((size_t)NPTS * HDIM * sizeof(float));
    float*          hB0    = (float*) alloc((size_t)NPTS * HDIM * sizeof(float));
    float*          hC0    = (float*) alloc((size_t)NPTS * HDIM * sizeof(float));
    float*          hA1    = (float*) alloc((size_t)NPTS * HDIM * sizeof(float));
    float*          hB1    = (float*) alloc((size_t)NPTS * HDIM * sizeof(float));
    float*          hC1    = (float*) alloc((size_t)NPTS * HDIM * sizeof(float));
    // hist and bar ADJACENT so one memset zeroes both; btot is WT-written
    // before first read (no zeroing needed).
    int*            hist   = (int*)   alloc(GC * sizeof(int));
    int*            bar    = (int*)   alloc(BARINTS * sizeof(int));
    int*            btot   = (int*)   alloc(NBLK * sizeof(int));

    const size_t zbytes = (size_t)((char*)bar + BARINTS * sizeof(int) - (char*)hist);
    hipMemsetAsync(hist, 0, zbytes, stream);

    mega_kernel<<<NBLK, KTHR, 0, stream>>>(seed, hist, btot, cursor, bxy, bid,
                                           xb, cs16, W1, W2, W3, W4, xb1,
                                           hA0, hB0, hC0, hA1, hB1, hC1,
                                           out, bar);
}